// Round 1
// baseline (357.716 us; speedup 1.0000x reference)
//
#include <hip/hip_runtime.h>
#include <math.h>

// Problem constants (from reference init_kwargs)
#define NB 32
#define NS 512
#define NSAMP 8      // NUM_SAMPLES
#define NEXP 256     // NUM_EXP
#define KBOUND 40    // NUM_SAMPLES_BOUNDARY
#define NMARK 10     // NUM_MARK
#define DTIME_MAX 5.0f
#define OVER_SAMPLE 1.5f

// jax.nn.softplus(x) = logaddexp(x, 0) = max(x,0) + log1p(exp(-|x|))
__device__ __forceinline__ float softplus_ref(float x) {
    float mx = fmaxf(x, 0.0f);
    return __fadd_rn(mx, log1pf(expf(-fabsf(x))));
}

__global__ __launch_bounds__(256) void syn_event_sampler(
    const float* __restrict__ time_seq,   // [B,S]
    const float* __restrict__ dt_seq,     // [B,S]
    const int*   __restrict__ event_seq,  // [B,S]
    const float* __restrict__ exp_raw,    // [B,S,E]
    const float* __restrict__ unif,       // [B,S,NSAMP,E]
    const float* __restrict__ emb,        // [20, NMARK]
    const float* __restrict__ scale,      // [NMARK]
    const float* __restrict__ bias,       // [NMARK]
    float* __restrict__ out_res,          // [B,S,NSAMP]
    float* __restrict__ out_w)            // [B,S,NSAMP]
{
    const int bs  = blockIdx.x;       // flat (b,s) index, 0..16383
    const int tid = threadIdx.x;      // 0..255 == exp-sample index

    __shared__ float s_em[NMARK], s_sc[NMARK], s_bi[NMARK];
    __shared__ float s_bound[KBOUND];
    __shared__ float s_red[4];

    const int ev = event_seq[bs];
    if (tid < NMARK) {
        s_em[tid] = emb[ev * NMARK + tid];
        s_sc[tid] = scale[tid];
        s_bi[tid] = bias[tid];
    }
    __syncthreads();

    // per-mark params into registers (broadcast LDS reads)
    float em[NMARK], sc[NMARK], bi[NMARK];
    #pragma unroll
    for (int m = 0; m < NMARK; ++m) { em[m] = s_em[m]; sc[m] = s_sc[m]; bi[m] = s_bi[m]; }

    const float t  = time_seq[bs];
    const float dt = dt_seq[bs];

    // ---- compute_intensity_upper_bound ----
    // lin[k] = k * (1/39) in fp32, matching jnp.linspace(0,1,40) step formulation
    if (tid < KBOUND) {
        const float step = 1.0f / 39.0f;           // compile-time correctly-rounded
        float lin = __fmul_rn((float)tid, step);
        float tb  = __fadd_rn(t, __fmul_rn(dt, lin));   // t + dt*lin (no FMA)
        float c   = cosf(tb);
        float sum = 0.0f;
        #pragma unroll
        for (int m = 0; m < NMARK; ++m) {
            // (emb + scale*cos) + bias, left-to-right, no contraction
            float x = __fadd_rn(__fadd_rn(em[m], __fmul_rn(sc[m], c)), bi[m]);
            sum = __fadd_rn(sum, softplus_ref(x));
        }
        s_bound[tid] = sum;
    }
    __syncthreads();

    float mx = s_bound[0];
    #pragma unroll
    for (int k = 1; k < KBOUND; ++k) mx = fmaxf(mx, s_bound[k]);
    const float upper = __fmul_rn(mx, OVER_SAMPLE);

    // ---- sample_exp_distribution + intensities at sampled times ----
    const float eraw = exp_raw[(size_t)bs * NEXP + tid];
    const float expn = eraw / upper;               // IEEE fp32 division
    const float tex  = __fadd_rn(t, expn);         // time_seq + exp_numbers
    const float c    = cosf(tex);
    float total = 0.0f;
    #pragma unroll
    for (int m = 0; m < NMARK; ++m) {
        float x = __fadd_rn(__fadd_rn(em[m], __fmul_rn(sc[m], c)), bi[m]);
        total = __fadd_rn(total, softplus_ref(x));
    }

    // ---- sample_accept: per-ns block-min over accepted exp_numbers ----
    const size_t ubase = (size_t)bs * NSAMP * NEXP;
    for (int ns = 0; ns < NSAMP; ++ns) {
        float u    = unif[ubase + (size_t)ns * NEXP + tid];
        // criterion = (unif * upper) / total_int  — exact ref op order, IEEE div
        float crit = __fmul_rn(u, upper) / total;
        float cand = (crit < 1.0f) ? expn : INFINITY;

        // wave-level min (64 lanes)
        #pragma unroll
        for (int off = 32; off > 0; off >>= 1)
            cand = fminf(cand, __shfl_down(cand, off, 64));
        if ((tid & 63) == 0) s_red[tid >> 6] = cand;
        __syncthreads();
        if (tid == 0) {
            float m0 = fminf(fminf(s_red[0], s_red[1]), fminf(s_red[2], s_red[3]));
            float r  = isinf(m0) ? DTIME_MAX : m0;
            r = fminf(r, 1e5f);
            out_res[(size_t)bs * NSAMP + ns] = r;
            out_w  [(size_t)bs * NSAMP + ns] = 0.125f;
        }
        __syncthreads();
    }
}

extern "C" void kernel_launch(void* const* d_in, const int* in_sizes, int n_in,
                              void* d_out, int out_size, void* d_ws, size_t ws_size,
                              hipStream_t stream) {
    const float* time_seq = (const float*)d_in[0];
    const float* dt_seq   = (const float*)d_in[1];
    const int*   ev_seq   = (const int*)  d_in[2];
    const float* exp_raw  = (const float*)d_in[3];
    const float* unif     = (const float*)d_in[4];
    const float* emb      = (const float*)d_in[5];
    const float* scale    = (const float*)d_in[6];
    const float* bias     = (const float*)d_in[7];

    float* out_res = (float*)d_out;                       // [B,S,NSAMP]
    float* out_w   = out_res + (size_t)NB * NS * NSAMP;   // [B,S,NSAMP]

    dim3 grid(NB * NS);
    dim3 block(NEXP);
    syn_event_sampler<<<grid, block, 0, stream>>>(
        time_seq, dt_seq, ev_seq, exp_raw, unif, emb, scale, bias, out_res, out_w);
}

// Round 2
// 217.411 us; speedup vs baseline: 1.6453x; 1.6453x over previous
//
#include <hip/hip_runtime.h>
#include <math.h>

// Problem constants (from reference init_kwargs)
#define NBATCH 32
#define NSEQ 512
#define NSAMP 8      // NUM_SAMPLES
#define NEXP 256     // NUM_EXP
#define KBOUND 40    // NUM_SAMPLES_BOUNDARY
#define NMARK 10     // NUM_MARK
#define DTIME_MAX 5.0f
#define OVER_SAMPLE 1.5f

// cos(x) via 2-term Cody-Waite reduction in revolution space + v_cos_f32.
// v_cos_f32 computes cos(2*pi*f). Reduction error ~3e-8 rev for |x| <= ~400.
__device__ __forceinline__ float fast_cos(float x) {
    constexpr double inv2pi_d = 0.15915494309189535;
    constexpr float chi = (float)inv2pi_d;
    constexpr float clo = (float)(inv2pi_d - (double)chi);
    float n = rintf(x * chi);            // v_rndne; off-by-one is cos-periodic (f -> f-1)
    float f = fmaf(x, chi, -n);          // exact-ish fractional part
    f = fmaf(x, clo, f);                 // second Cody-Waite term
    return __builtin_amdgcn_cosf(f);
}

// sum_m softplus(eb[m] + sc[m]*c) via the log-product identity:
//   sum softplus(x) = sum max(x,0) + ln2 * log2( prod (1 + 2^(-|x|*log2e)) )
// Each factor in (1,2] -> product <= 2^10, no overflow. 11 transcendental instrs.
__device__ __forceinline__ float intensity_sum(float c, const float eb[NMARK],
                                               const float sc[NMARK]) {
    const float NLOG2E = -1.4426950408889634f;
    const float LN2    =  0.69314718055994531f;
    float acc0 = 0.f, acc1 = 0.f, p0 = 1.f, p1 = 1.f;
    #pragma unroll
    for (int m = 0; m < NMARK; m += 2) {
        float x0 = fmaf(sc[m],     c, eb[m]);
        float x1 = fmaf(sc[m + 1], c, eb[m + 1]);
        float e0 = __builtin_amdgcn_exp2f(fabsf(x0) * NLOG2E);
        float e1 = __builtin_amdgcn_exp2f(fabsf(x1) * NLOG2E);
        p0 *= (1.f + e0);
        p1 *= (1.f + e1);
        acc0 += fmaxf(x0, 0.f);
        acc1 += fmaxf(x1, 0.f);
    }
    return fmaf(LN2, __builtin_amdgcn_logf(p0 * p1), acc0 + acc1);
}

__global__ __launch_bounds__(256) void syn_event_sampler(
    const float* __restrict__ time_seq,   // [B,S]
    const float* __restrict__ dt_seq,     // [B,S]
    const int*   __restrict__ event_seq,  // [B,S]
    const float* __restrict__ exp_raw,    // [B,S,E]
    const float* __restrict__ unif,       // [B,S,NSAMP,E]
    const float* __restrict__ emb,        // [20, NMARK]
    const float* __restrict__ scale,      // [NMARK]
    const float* __restrict__ bias,       // [NMARK]
    float* __restrict__ out_res,          // [B,S,NSAMP]
    float* __restrict__ out_w)            // [B,S,NSAMP]
{
    const int bs   = blockIdx.x;      // flat (b,s)
    const int tid  = threadIdx.x;     // 0..255 == exp-sample index
    const int lane = tid & 63;
    const int wv   = tid >> 6;

    __shared__ float s_eb[NMARK], s_sc[NMARK];
    __shared__ float s_bmax[4];
    __shared__ float s_red[4][NSAMP];

    if (tid < NMARK) {
        int ev = event_seq[bs];
        s_eb[tid] = emb[ev * NMARK + tid] + bias[tid];  // fold bias into emb
        s_sc[tid] = scale[tid];
    }
    __syncthreads();

    float eb[NMARK], sc[NMARK];
    #pragma unroll
    for (int m = 0; m < NMARK; ++m) { eb[m] = s_eb[m]; sc[m] = s_sc[m]; }

    const float t   = time_seq[bs];
    const float dtv = dt_seq[bs];

    // ---- upper bound: 40 boundary points, 10 per wave (balances SIMDs) ----
    float bsum = -INFINITY;
    if (lane < 10) {
        int k = wv * 10 + lane;
        const float step = 1.0f / 39.0f;
        // t + dt*lin with no FMA contraction (matches ref op order)
        float tb = __fadd_rn(t, __fmul_rn(dtv, __fmul_rn((float)k, step)));
        bsum = intensity_sum(fast_cos(tb), eb, sc);
    }
    #pragma unroll
    for (int off = 1; off < 64; off <<= 1)
        bsum = fmaxf(bsum, __shfl_xor(bsum, off, 64));
    if (lane == 0) s_bmax[wv] = bsum;
    __syncthreads();
    const float upper =
        fmaxf(fmaxf(s_bmax[0], s_bmax[1]), fmaxf(s_bmax[2], s_bmax[3])) * OVER_SAMPLE;

    // ---- per-exp-sample intensity ----
    const float eraw  = exp_raw[(size_t)bs * NEXP + tid];
    const float expn  = eraw / upper;              // IEEE div, once per thread
    const float total = intensity_sum(fast_cos(t + expn), eb, sc);

    // ---- accept + per-ns min ----
    // criterion < 1  <=>  u*upper < total  (all positive; flips only in ~2^-25 band)
    const float* up = unif + (size_t)bs * NSAMP * NEXP + tid;
    float cand[NSAMP];
    #pragma unroll
    for (int ns = 0; ns < NSAMP; ++ns) {
        float u = up[(size_t)ns * NEXP];           // 8 independent loads, all in flight
        cand[ns] = (__fmul_rn(u, upper) < total) ? expn : INFINITY;
    }
    #pragma unroll
    for (int ns = 0; ns < NSAMP; ++ns) {
        float v = cand[ns];
        #pragma unroll
        for (int off = 1; off < 64; off <<= 1)
            v = fminf(v, __shfl_xor(v, off, 64));  // DS pipe, offloads VALU
        if (lane == 0) s_red[wv][ns] = v;
    }
    __syncthreads();

    if (tid < NSAMP) {
        float m0 = fminf(fminf(s_red[0][tid], s_red[1][tid]),
                         fminf(s_red[2][tid], s_red[3][tid]));
        float r = isinf(m0) ? DTIME_MAX : m0;
        r = fminf(r, 1e5f);
        out_res[(size_t)bs * NSAMP + tid] = r;
        out_w  [(size_t)bs * NSAMP + tid] = 1.0f / NSAMP;
    }
}

extern "C" void kernel_launch(void* const* d_in, const int* in_sizes, int n_in,
                              void* d_out, int out_size, void* d_ws, size_t ws_size,
                              hipStream_t stream) {
    const float* time_seq = (const float*)d_in[0];
    const float* dt_seq   = (const float*)d_in[1];
    const int*   ev_seq   = (const int*)  d_in[2];
    const float* exp_raw  = (const float*)d_in[3];
    const float* unif     = (const float*)d_in[4];
    const float* emb      = (const float*)d_in[5];
    const float* scale    = (const float*)d_in[6];
    const float* bias     = (const float*)d_in[7];

    float* out_res = (float*)d_out;                          // [B,S,NSAMP]
    float* out_w   = out_res + (size_t)NBATCH * NSEQ * NSAMP;

    dim3 grid(NBATCH * NSEQ);
    dim3 block(NEXP);
    syn_event_sampler<<<grid, block, 0, stream>>>(
        time_seq, dt_seq, ev_seq, exp_raw, unif, emb, scale, bias, out_res, out_w);
}

// Round 3
// 213.865 us; speedup vs baseline: 1.6726x; 1.0166x over previous
//
#include <hip/hip_runtime.h>
#include <math.h>

// Problem constants (from reference init_kwargs)
#define NBATCH 32
#define NSEQ 512
#define NSAMP 8      // NUM_SAMPLES
#define NEXP 256     // NUM_EXP
#define KBOUND 40    // NUM_SAMPLES_BOUNDARY
#define NMARK 10     // NUM_MARK
#define DTIME_MAX 5.0f
#define OVER_SAMPLE 1.5f

// cos(x) via 2-term Cody-Waite reduction in revolution space + v_cos_f32.
// v_cos_f32 computes cos(2*pi*f). Reduction error ~3e-8 rev for |x| <= ~400.
__device__ __forceinline__ float fast_cos(float x) {
    constexpr double inv2pi_d = 0.15915494309189535;
    constexpr float chi = (float)inv2pi_d;
    constexpr float clo = (float)(inv2pi_d - (double)chi);
    float n = rintf(x * chi);
    float f = fmaf(x, chi, -n);
    f = fmaf(x, clo, f);
    return __builtin_amdgcn_cosf(f);
}

// sum_m softplus(eb[m] + sc[m]*c) via the log-product identity:
//   sum softplus(x) = sum max(x,0) + ln2 * log2( prod (1 + 2^(-|x|*log2e)) )
// Each factor in (1,2] -> product <= 2^10, no overflow. 11 transcendental instrs.
// (validated bit-clean vs np reference in R2)
__device__ __forceinline__ float intensity_sum(float c, const float eb[NMARK],
                                               const float sc[NMARK]) {
    const float NLOG2E = -1.4426950408889634f;
    const float LN2    =  0.69314718055994531f;
    float acc0 = 0.f, acc1 = 0.f, p0 = 1.f, p1 = 1.f;
    #pragma unroll
    for (int m = 0; m < NMARK; m += 2) {
        float x0 = fmaf(sc[m],     c, eb[m]);
        float x1 = fmaf(sc[m + 1], c, eb[m + 1]);
        float e0 = __builtin_amdgcn_exp2f(fabsf(x0) * NLOG2E);
        float e1 = __builtin_amdgcn_exp2f(fabsf(x1) * NLOG2E);
        p0 *= (1.f + e0);
        p1 *= (1.f + e1);
        acc0 += fmaxf(x0, 0.f);
        acc1 += fmaxf(x1, 0.f);
    }
    return fmaf(LN2, __builtin_amdgcn_logf(p0 * p1), acc0 + acc1);
}

__device__ __forceinline__ float rfl_f(float x) {
    return __int_as_float(__builtin_amdgcn_readfirstlane(__float_as_int(x)));
}

// One wave per (b,s). Lane l owns exp-samples 4l..4l+3 (float4-coalesced).
// No LDS, no barriers — all reductions are wave shuffles.
__global__ __launch_bounds__(256) void syn_event_sampler(
    const float* __restrict__ time_seq,   // [B,S]
    const float* __restrict__ dt_seq,     // [B,S]
    const int*   __restrict__ event_seq,  // [B,S]
    const float* __restrict__ exp_raw,    // [B,S,E]
    const float* __restrict__ unif,       // [B,S,NSAMP,E]
    const float* __restrict__ emb,        // [20, NMARK]
    const float* __restrict__ scale,      // [NMARK]
    const float* __restrict__ bias,       // [NMARK]
    float* __restrict__ out_res,          // [B,S,NSAMP]
    float* __restrict__ out_w)            // [B,S,NSAMP]
{
    const int lane = threadIdx.x & 63;
    const int wv   = threadIdx.x >> 6;
    const int bs   = blockIdx.x * 4 + wv;      // one (b,s) per wave

    // ---- issue all streaming loads up front (9 x dwordx4 per lane) ----
    const float4 er4 = *reinterpret_cast<const float4*>(
        exp_raw + (size_t)bs * NEXP + 4 * lane);
    const float* ub = unif + (size_t)bs * NSAMP * NEXP + 4 * lane;
    float4 u4[NSAMP];
    #pragma unroll
    for (int ns = 0; ns < NSAMP; ++ns)
        u4[ns] = *reinterpret_cast<const float4*>(ub + (size_t)ns * NEXP);

    // ---- wave-uniform scalars (hoist to SGPRs) ----
    const float t   = rfl_f(time_seq[bs]);
    const float dtv = rfl_f(dt_seq[bs]);
    const int   ev  = __builtin_amdgcn_readfirstlane(event_seq[bs]);

    float eb[NMARK], sc[NMARK];
    #pragma unroll
    for (int m = 0; m < NMARK; ++m) {
        eb[m] = emb[ev * NMARK + m] + bias[m];  // bias==0 in data; fold is exact
        sc[m] = scale[m];
    }

    // ---- upper bound: 40 boundary points on lanes 0..39, wave max ----
    float bsum = -INFINITY;
    if (lane < KBOUND) {
        const float step = 1.0f / 39.0f;
        float tb = __fadd_rn(t, __fmul_rn(dtv, __fmul_rn((float)lane, step)));
        bsum = intensity_sum(fast_cos(tb), eb, sc);
    }
    #pragma unroll
    for (int off = 1; off < 64; off <<= 1)
        bsum = fmaxf(bsum, __shfl_xor(bsum, off, 64));
    const float upper = bsum * OVER_SAMPLE;

    // ---- per-exp-sample intensities (4 per lane) ----
    float expn[4], total[4];
    expn[0] = er4.x / upper;  expn[1] = er4.y / upper;
    expn[2] = er4.z / upper;  expn[3] = er4.w / upper;
    #pragma unroll
    for (int i = 0; i < 4; ++i)
        total[i] = intensity_sum(fast_cos(t + expn[i]), eb, sc);

    // ---- accept + per-ns wave min; criterion<1 <=> u*upper < total ----
    float vmin[NSAMP];
    #pragma unroll
    for (int ns = 0; ns < NSAMP; ++ns) {
        float c0 = (__fmul_rn(u4[ns].x, upper) < total[0]) ? expn[0] : INFINITY;
        float c1 = (__fmul_rn(u4[ns].y, upper) < total[1]) ? expn[1] : INFINITY;
        float c2 = (__fmul_rn(u4[ns].z, upper) < total[2]) ? expn[2] : INFINITY;
        float c3 = (__fmul_rn(u4[ns].w, upper) < total[3]) ? expn[3] : INFINITY;
        float v = fminf(fminf(c0, c1), fminf(c2, c3));
        #pragma unroll
        for (int off = 1; off < 64; off <<= 1)
            v = fminf(v, __shfl_xor(v, off, 64));
        vmin[ns] = v;
    }

    // ---- select vmin[lane] via cndmask chain; lanes 0..7 store ----
    float rv = vmin[0];
    #pragma unroll
    for (int ns = 1; ns < NSAMP; ++ns)
        rv = (lane == ns) ? vmin[ns] : rv;
    if (lane < NSAMP) {
        float r = isinf(rv) ? DTIME_MAX : rv;
        r = fminf(r, 1e5f);
        out_res[(size_t)bs * NSAMP + lane] = r;
        out_w  [(size_t)bs * NSAMP + lane] = 1.0f / NSAMP;
    }
}

extern "C" void kernel_launch(void* const* d_in, const int* in_sizes, int n_in,
                              void* d_out, int out_size, void* d_ws, size_t ws_size,
                              hipStream_t stream) {
    const float* time_seq = (const float*)d_in[0];
    const float* dt_seq   = (const float*)d_in[1];
    const int*   ev_seq   = (const int*)  d_in[2];
    const float* exp_raw  = (const float*)d_in[3];
    const float* unif     = (const float*)d_in[4];
    const float* emb      = (const float*)d_in[5];
    const float* scale    = (const float*)d_in[6];
    const float* bias     = (const float*)d_in[7];

    float* out_res = (float*)d_out;                          // [B,S,NSAMP]
    float* out_w   = out_res + (size_t)NBATCH * NSEQ * NSAMP;

    dim3 grid((NBATCH * NSEQ) / 4);   // one wave per (b,s), 4 waves/block
    dim3 block(256);
    syn_event_sampler<<<grid, block, 0, stream>>>(
        time_seq, dt_seq, ev_seq, exp_raw, unif, emb, scale, bias, out_res, out_w);
}